// Round 4
// baseline (217.325 us; speedup 1.0000x reference)
//
#include <hip/hip_runtime.h>

// Multi-Scale Deformable Attention forward, fp32.
//   value:  (B=2, Len=21760, nH=8, D=32) fp32
//   loc:    (B, Q=21760, nH, L=4, P=4, 2) fp32
//   attw:   (B, Q, nH, L, P) fp32
//   out:    (B, Q, nH*D=256) fp32
// Levels: (128,128),(64,64),(32,32),(16,16), starts 0,16384,20480,21504.
//
// 8 threads per (b,q,h); thread `sub` owns channels [sub*4, sub*4+4).
// Round-3 post-mortem: compiler re-serializes source-level load batches
// (VGPR=32 -> ~2 loads in flight, latency-bound). Here the 16 gathers per
// level are issued via asm volatile global_load_dwordx4 (cannot be
// reordered), then ONE vmcnt(0) + sched_barrier(0), then the FMAs.

namespace {
constexpr int kB   = 2;
constexpr int kQ   = 21760;
constexpr int kHd  = 8;
constexpr int kD   = 32;
constexpr int kLen = 21760;
constexpr int kRow = kHd * kD;   // 256 floats per spatial position
}

typedef float f32x4 __attribute__((ext_vector_type(4)));

__global__ __launch_bounds__(256, 3) void msda_fwd(
    const float* __restrict__ value,
    const float* __restrict__ loc,
    const float* __restrict__ attw,
    float* __restrict__ out)
{
    const int t   = blockIdx.x * 256 + threadIdx.x;
    const int sub = t & 7;          // float4 slot within the 32-ch head
    const int g   = t >> 3;         // (b*Q + q)*8 + h
    const int h   = g & 7;
    const int bq  = g >> 3;         // b*Q + q
    const int b   = (bq >= kQ) ? 1 : 0;   // B == 2, avoid idiv

    const float4* lp4 = (const float4*)(loc  + (size_t)g * 32);
    const float4* ap4 = (const float4*)(attw + (size_t)g * 16);
    // 32-bit byte offset of this thread's channel slice within `value`
    const int thrbase = ((b * kLen * kRow) + h * kD + sub * 4) * 4;
    const char* vbase = (const char*)value;

    f32x4 acc = {0.f, 0.f, 0.f, 0.f};

    constexpr int Hs[4] = {128, 64, 32, 16};
    constexpr int Ws[4] = {128, 64, 32, 16};
    constexpr int Ss[4] = {0, 16384, 20480, 21504};

    #pragma unroll
    for (int l = 0; l < 4; ++l) {
        const int W = Ws[l];
        const int H = Hs[l];
        const int base = thrbase + (Ss[l] << 10);   // S * kRow * 4 bytes

        const float4 lc0 = lp4[2 * l];
        const float4 lc1 = lp4[2 * l + 1];
        const float4 av  = ap4[l];

        const float lx[4] = {lc0.x, lc0.z, lc1.x, lc1.z};
        const float ly[4] = {lc0.y, lc0.w, lc1.y, lc1.w};
        const float aa[4] = {av.x,  av.y,  av.z,  av.w};

        int   offs[16];
        float ws[16];

        #pragma unroll
        for (int p = 0; p < 4; ++p) {
            // grid_sample(align_corners=False): x = loc_x * W - 0.5
            const float x = fmaf(lx[p], (float)W, -0.5f);
            const float y = fmaf(ly[p], (float)H, -0.5f);
            const float x0f = floorf(x);
            const float y0f = floorf(y);
            const float fx = x - x0f;
            const float fy = y - y0f;
            const int   x0 = (int)x0f;
            const int   y0 = (int)y0f;
            const float a  = aa[p];

            const bool vx0 = (unsigned)x0       < (unsigned)W;
            const bool vx1 = (unsigned)(x0 + 1) < (unsigned)W;
            const bool vy0 = (unsigned)y0       < (unsigned)H;
            const bool vy1 = (unsigned)(y0 + 1) < (unsigned)H;

            const int xc0 = min(max(x0, 0),     W - 1);
            const int xc1 = min(max(x0 + 1, 0), W - 1);
            const int yc0 = min(max(y0, 0),     H - 1);
            const int yc1 = min(max(y0 + 1, 0), H - 1);

            const float w00 = a * (1.f - fx) * (1.f - fy);
            const float w01 = a * fx * (1.f - fy);
            const float w10 = a * (1.f - fx) * fy;
            const float w11 = a * fx * fy;

            ws[p * 4 + 0] = (vy0 && vx0) ? w00 : 0.f;
            ws[p * 4 + 1] = (vy0 && vx1) ? w01 : 0.f;
            ws[p * 4 + 2] = (vy1 && vx0) ? w10 : 0.f;
            ws[p * 4 + 3] = (vy1 && vx1) ? w11 : 0.f;

            const int r0 = yc0 * W;   // W is power of two -> shift
            const int r1 = yc1 * W;
            offs[p * 4 + 0] = base + ((r0 + xc0) << 10);
            offs[p * 4 + 1] = base + ((r0 + xc1) << 10);
            offs[p * 4 + 2] = base + ((r1 + xc0) << 10);
            offs[p * 4 + 3] = base + ((r1 + xc1) << 10);
        }

        // Issue all 16 gathers back-to-back; volatile asm pins issue order.
        f32x4 tv[16];
        #pragma unroll
        for (int i = 0; i < 16; ++i) {
            const void* p = vbase + offs[i];
            asm volatile("global_load_dwordx4 %0, %1, off"
                         : "=v"(tv[i]) : "v"(p) : "memory");
        }
        asm volatile("s_waitcnt vmcnt(0)" ::: "memory");
        __builtin_amdgcn_sched_barrier(0);   // rule #18: keep FMAs below wait

        #pragma unroll
        for (int i = 0; i < 16; ++i) {
            acc.x = fmaf(ws[i], tv[i].x, acc.x);
            acc.y = fmaf(ws[i], tv[i].y, acc.y);
            acc.z = fmaf(ws[i], tv[i].z, acc.z);
            acc.w = fmaf(ws[i], tv[i].w, acc.w);
        }
    }

    float4 r;
    r.x = acc.x; r.y = acc.y; r.z = acc.z; r.w = acc.w;
    *(float4*)(out + (size_t)bq * kRow + h * kD + sub * 4) = r;
}

extern "C" void kernel_launch(void* const* d_in, const int* in_sizes, int n_in,
                              void* d_out, int out_size, void* d_ws, size_t ws_size,
                              hipStream_t stream) {
    const float* value = (const float*)d_in[0];
    const float* loc   = (const float*)d_in[3];
    const float* attw  = (const float*)d_in[4];
    float* out = (float*)d_out;

    const int total_threads = kB * kQ * kHd * 8;   // 2,785,280
    const int block = 256;
    const int grid  = total_threads / block;       // 10880 exactly

    msda_fwd<<<grid, block, 0, stream>>>(value, loc, attw, out);
}

// Round 5
// 153.423 us; speedup vs baseline: 1.4165x; 1.4165x over previous
//
#include <hip/hip_runtime.h>

// Multi-Scale Deformable Attention forward, fp32.
//   value:  (B=2, Len=21760, nH=8, D=32) fp32
//   loc:    (B, Q=21760, nH, L=4, P=4, 2) fp32
//   attw:   (B, Q, nH, L, P) fp32
//   out:    (B, Q, nH*D=256) fp32
// Levels: (128,128),(64,64),(32,32),(16,16), starts 0,16384,20480,21504.
//
// Round-4 diagnosis: ~3.5 TB/s L2-miss (random 128-B gather) ceiling;
// invariant under MLP/occupancy changes. Fix: each block handles ONE
// (b,h) pair; pair's value slice = 2.78 MB < 4 MB per-XCD L2. Map
// pair -> XCD via blockIdx%8 round-robin so each XCD's L2 holds exactly
// its head's slice. 8 threads per (b,q,h); thread `sub` owns channels
// [sub*4, sub*4+4). 32 queries per 256-thread block.

namespace {
constexpr int kB    = 2;
constexpr int kQ    = 21760;
constexpr int kHd   = 8;
constexpr int kD    = 32;
constexpr int kLen  = 21760;
constexpr int kRow  = kHd * kD;      // 256 floats per spatial position
constexpr int kQBlk = 32;            // queries per block
constexpr int kBlksPerPair = kQ / kQBlk;   // 680
}

__device__ __forceinline__ void fma4(float4& a, float w, const float4 v) {
    a.x = fmaf(w, v.x, a.x);
    a.y = fmaf(w, v.y, a.y);
    a.z = fmaf(w, v.z, a.z);
    a.w = fmaf(w, v.w, a.w);
}

__global__ __launch_bounds__(256, 4) void msda_fwd(
    const float* __restrict__ value,
    const float* __restrict__ loc,
    const float* __restrict__ attw,
    float* __restrict__ out)
{
    // blockIdx -> (xcd, k); XCD x runs pair (b=0,h=x) then (b=1,h=x).
    const int i    = blockIdx.x;
    const int xcd  = i & 7;
    const int k    = i >> 3;                      // 0..2*kBlksPerPair-1
    const int b    = (k >= kBlksPerPair) ? 1 : 0;
    const int j    = k - b * kBlksPerPair;        // q-block within pair
    const int h    = xcd;

    const int qi   = threadIdx.x >> 3;            // 0..31
    const int sub  = threadIdx.x & 7;             // channel float4 slot
    const int q    = j * kQBlk + qi;
    const int g    = (b * kQ + q) * kHd + h;

    const float4* lp4 = (const float4*)(loc  + (size_t)g * 32);
    const float4* ap4 = (const float4*)(attw + (size_t)g * 16);
    const float*  vb  = value + (size_t)b * kLen * kRow + h * kD + sub * 4;

    float4 acc = make_float4(0.f, 0.f, 0.f, 0.f);

    constexpr int Hs[4] = {128, 64, 32, 16};
    constexpr int Ws[4] = {128, 64, 32, 16};
    constexpr int Ss[4] = {0, 16384, 20480, 21504};

    #pragma unroll
    for (int l = 0; l < 4; ++l) {
        const int W = Ws[l];
        const int H = Hs[l];
        const int S = Ss[l];

        const float4 lc0 = lp4[2 * l];
        const float4 lc1 = lp4[2 * l + 1];
        const float4 av  = ap4[l];

        const float lx[4] = {lc0.x, lc0.z, lc1.x, lc1.z};
        const float ly[4] = {lc0.y, lc0.w, lc1.y, lc1.w};
        const float aa[4] = {av.x,  av.y,  av.z,  av.w};

        #pragma unroll
        for (int p = 0; p < 4; ++p) {
            // grid_sample(align_corners=False): x = loc_x * W - 0.5
            const float x = fmaf(lx[p], (float)W, -0.5f);
            const float y = fmaf(ly[p], (float)H, -0.5f);
            const float x0f = floorf(x);
            const float y0f = floorf(y);
            const float fx = x - x0f;
            const float fy = y - y0f;
            const int   x0 = (int)x0f;
            const int   y0 = (int)y0f;
            const float a  = aa[p];

            const bool vx0 = (unsigned)x0       < (unsigned)W;
            const bool vx1 = (unsigned)(x0 + 1) < (unsigned)W;
            const bool vy0 = (unsigned)y0       < (unsigned)H;
            const bool vy1 = (unsigned)(y0 + 1) < (unsigned)H;

            const int xc0 = min(max(x0, 0),     W - 1);
            const int xc1 = min(max(x0 + 1, 0), W - 1);
            const int yc0 = min(max(y0, 0),     H - 1);
            const int yc1 = min(max(y0 + 1, 0), H - 1);

            float w00 = a * (1.f - fx) * (1.f - fy);
            float w01 = a * fx * (1.f - fy);
            float w10 = a * (1.f - fx) * fy;
            float w11 = a * fx * fy;
            w00 = (vy0 && vx0) ? w00 : 0.f;
            w01 = (vy0 && vx1) ? w01 : 0.f;
            w10 = (vy1 && vx0) ? w10 : 0.f;
            w11 = (vy1 && vx1) ? w11 : 0.f;

            const int r0 = (S + yc0 * W) * kRow;
            const int r1 = (S + yc1 * W) * kRow;
            const float4 v00 = *(const float4*)(vb + r0 + xc0 * kRow);
            const float4 v01 = *(const float4*)(vb + r0 + xc1 * kRow);
            const float4 v10 = *(const float4*)(vb + r1 + xc0 * kRow);
            const float4 v11 = *(const float4*)(vb + r1 + xc1 * kRow);

            fma4(acc, w00, v00);
            fma4(acc, w01, v01);
            fma4(acc, w10, v10);
            fma4(acc, w11, v11);
        }
    }

    *(float4*)(out + ((size_t)(b * kQ + q)) * kRow + h * kD + sub * 4) = acc;
}

extern "C" void kernel_launch(void* const* d_in, const int* in_sizes, int n_in,
                              void* d_out, int out_size, void* d_ws, size_t ws_size,
                              hipStream_t stream) {
    const float* value = (const float*)d_in[0];
    const float* loc   = (const float*)d_in[3];
    const float* attw  = (const float*)d_in[4];
    float* out = (float*)d_out;

    const int grid = kB * kHd * kBlksPerPair;   // 16 pairs * 680 = 10880
    msda_fwd<<<grid, 256, 0, stream>>>(value, loc, attw, out);
}

// Round 7
// 140.431 us; speedup vs baseline: 1.5476x; 1.0925x over previous
//
#include <hip/hip_runtime.h>

// Multi-Scale Deformable Attention forward, fp32.
//   value:  (B=2, Len=21760, nH=8, D=32) fp32
//   loc:    (B, Q=21760, nH, L=4, P=4, 2) fp32
//   attw:   (B, Q, nH, L, P) fp32
//   out:    (B, Q, nH*D=256) fp32
// Levels: (128,128),(64,64),(32,32),(16,16), starts 0,16384,20480,21504.
//
// Composition of the two PROVEN-correct configs:
//  * R5: one (b,h) pair per block, pair -> XCD via blockIdx%8; each XCD's
//    4-MB L2 holds its head's 2.78-MB value slice (FETCH 735->118 MB).
//  * R4: 16 gathers per level via asm volatile global_load_dwordx4,
//    SINGLE s_waitcnt vmcnt(0) + sched_barrier drain, launch_bounds(256,3)
//    (VGPR=80, no spills — R6's counted vmcnt(8)+tighter cap faulted:
//    spill reloads under hidden-load asm break compiler waitcnt tracking).

namespace {
constexpr int kB    = 2;
constexpr int kQ    = 21760;
constexpr int kHd   = 8;
constexpr int kD    = 32;
constexpr int kLen  = 21760;
constexpr int kRow  = kHd * kD;            // 256 floats per spatial position
constexpr int kQBlk = 32;                  // queries per block
constexpr int kBlksPerPair = kQ / kQBlk;   // 680
}

typedef float f32x4 __attribute__((ext_vector_type(4)));

__global__ __launch_bounds__(256, 3) void msda_fwd(
    const float* __restrict__ value,
    const float* __restrict__ loc,
    const float* __restrict__ attw,
    float* __restrict__ out)
{
    // blockIdx -> (xcd, k); XCD x runs pair (b=0,h=x) then (b=1,h=x).
    const int i    = blockIdx.x;
    const int xcd  = i & 7;
    const int k    = i >> 3;
    const int b    = (k >= kBlksPerPair) ? 1 : 0;
    const int j    = k - b * kBlksPerPair;
    const int h    = xcd;

    const int qi   = threadIdx.x >> 3;     // 0..31
    const int sub  = threadIdx.x & 7;      // channel float4 slot
    const int q    = j * kQBlk + qi;
    const int g    = (b * kQ + q) * kHd + h;

    const float4* lp4 = (const float4*)(loc  + (size_t)g * 32);
    const float4* ap4 = (const float4*)(attw + (size_t)g * 16);
    // 32-bit byte offset of this thread's channel slice within `value`
    const int thrbase = ((b * kLen * kRow) + h * kD + sub * 4) * 4;
    const char* vbase = (const char*)value;

    f32x4 acc = {0.f, 0.f, 0.f, 0.f};

    constexpr int Hs[4] = {128, 64, 32, 16};
    constexpr int Ws[4] = {128, 64, 32, 16};
    constexpr int Ss[4] = {0, 16384, 20480, 21504};

    #pragma unroll
    for (int l = 0; l < 4; ++l) {
        const int W = Ws[l];
        const int H = Hs[l];
        const int base = thrbase + (Ss[l] << 10);   // S * kRow * 4 bytes

        const float4 lc0 = lp4[2 * l];
        const float4 lc1 = lp4[2 * l + 1];
        const float4 av  = ap4[l];

        const float lx[4] = {lc0.x, lc0.z, lc1.x, lc1.z};
        const float ly[4] = {lc0.y, lc0.w, lc1.y, lc1.w};
        const float aa[4] = {av.x,  av.y,  av.z,  av.w};

        int   offs[16];
        float ws[16];

        #pragma unroll
        for (int p = 0; p < 4; ++p) {
            // grid_sample(align_corners=False): x = loc_x * W - 0.5
            const float x = fmaf(lx[p], (float)W, -0.5f);
            const float y = fmaf(ly[p], (float)H, -0.5f);
            const float x0f = floorf(x);
            const float y0f = floorf(y);
            const float fx = x - x0f;
            const float fy = y - y0f;
            const int   x0 = (int)x0f;
            const int   y0 = (int)y0f;
            const float a  = aa[p];

            const bool vx0 = (unsigned)x0       < (unsigned)W;
            const bool vx1 = (unsigned)(x0 + 1) < (unsigned)W;
            const bool vy0 = (unsigned)y0       < (unsigned)H;
            const bool vy1 = (unsigned)(y0 + 1) < (unsigned)H;

            const int xc0 = min(max(x0, 0),     W - 1);
            const int xc1 = min(max(x0 + 1, 0), W - 1);
            const int yc0 = min(max(y0, 0),     H - 1);
            const int yc1 = min(max(y0 + 1, 0), H - 1);

            const float w00 = a * (1.f - fx) * (1.f - fy);
            const float w01 = a * fx * (1.f - fy);
            const float w10 = a * (1.f - fx) * fy;
            const float w11 = a * fx * fy;

            ws[p * 4 + 0] = (vy0 && vx0) ? w00 : 0.f;
            ws[p * 4 + 1] = (vy0 && vx1) ? w01 : 0.f;
            ws[p * 4 + 2] = (vy1 && vx0) ? w10 : 0.f;
            ws[p * 4 + 3] = (vy1 && vx1) ? w11 : 0.f;

            const int r0 = yc0 * W;   // W is power of two -> shift
            const int r1 = yc1 * W;
            offs[p * 4 + 0] = base + ((r0 + xc0) << 10);
            offs[p * 4 + 1] = base + ((r0 + xc1) << 10);
            offs[p * 4 + 2] = base + ((r1 + xc0) << 10);
            offs[p * 4 + 3] = base + ((r1 + xc1) << 10);
        }

        // Issue all 16 gathers back-to-back; volatile asm pins issue order.
        f32x4 tv[16];
        #pragma unroll
        for (int t16 = 0; t16 < 16; ++t16) {
            const void* p = vbase + offs[t16];
            asm volatile("global_load_dwordx4 %0, %1, off"
                         : "=v"(tv[t16]) : "v"(p) : "memory");
        }
        asm volatile("s_waitcnt vmcnt(0)" ::: "memory");
        __builtin_amdgcn_sched_barrier(0);   // rule #18: keep FMAs below wait

        #pragma unroll
        for (int t16 = 0; t16 < 16; ++t16) {
            acc.x = fmaf(ws[t16], tv[t16].x, acc.x);
            acc.y = fmaf(ws[t16], tv[t16].y, acc.y);
            acc.z = fmaf(ws[t16], tv[t16].z, acc.z);
            acc.w = fmaf(ws[t16], tv[t16].w, acc.w);
        }
    }

    float4 r;
    r.x = acc.x; r.y = acc.y; r.z = acc.z; r.w = acc.w;
    *(float4*)(out + ((size_t)(b * kQ + q)) * kRow + h * kD + sub * 4) = r;
}

extern "C" void kernel_launch(void* const* d_in, const int* in_sizes, int n_in,
                              void* d_out, int out_size, void* d_ws, size_t ws_size,
                              hipStream_t stream) {
    const float* value = (const float*)d_in[0];
    const float* loc   = (const float*)d_in[3];
    const float* attw  = (const float*)d_in[4];
    float* out = (float*)d_out;

    const int grid = kB * kHd * kBlksPerPair;   // 16 pairs * 680 = 10880
    msda_fwd<<<grid, 256, 0, stream>>>(value, loc, attw, out);
}